// Round 2
// baseline (1056.094 us; speedup 1.0000x reference)
//
#include <hip/hip_runtime.h>
#include <math.h>

#define HDIM 256
#define NSTATE 64
#define NDEPTH 4
#define LSEQ 2048
#define NBATCH 8
#define NROWS (NBATCH*LSEQ)   // 16384
#define HN (HDIM*NSTATE)      // 16384
#define INDIM 51
#define OUTC 204

// ---------------- cross-lane helpers (DPP, VALU pipe) ----------------
template<int CTRL>
__device__ __forceinline__ float dpp_add(float x) {
  int y = __builtin_amdgcn_update_dpp(0, __float_as_int(x), CTRL, 0xf, 0xf, true);
  return x + __int_as_float(y);
}
// full wave64 sum; total lands in lane 63
__device__ __forceinline__ float wave_sum64(float x) {
  x = dpp_add<0x111>(x);  // row_shr:1
  x = dpp_add<0x112>(x);  // row_shr:2
  x = dpp_add<0x114>(x);  // row_shr:4
  x = dpp_add<0x118>(x);  // row_shr:8
  x = dpp_add<0x142>(x);  // row_bcast:15
  x = dpp_add<0x143>(x);  // row_bcast:31
  return x;
}
__device__ __forceinline__ float rdlane(float v, int lane) {
  return __int_as_float(__builtin_amdgcn_readlane(__float_as_int(v), lane));
}
__device__ __forceinline__ float gelu_tanh(float x) {
  float x3 = x*x*x;
  return 0.5f*x*(1.f + tanhf(0.7978845608028654f*(x + 0.044715f*x3)));
}

// ---------------- input projection: x[16384,51] @ w[51,256] + b -> u[16384,256]
__global__ __launch_bounds__(256) void proj_kernel(
    const float* __restrict__ x, const float* __restrict__ w,
    const float* __restrict__ bias, float* __restrict__ u) {
  __shared__ float xs[8][52];  // padded rows, float4-aligned
  const int r0 = blockIdx.x * 8;
  const int tid = threadIdx.x;
  for (int idx = tid; idx < 8*INDIM; idx += 256) {
    int rr = idx / INDIM, k = idx % INDIM;
    xs[rr][k] = x[(size_t)(r0+rr)*INDIM + k];
  }
  __syncthreads();
  const int hcol = tid;
  float acc[8];
  const float bb = bias[hcol];
#pragma unroll
  for (int rr = 0; rr < 8; ++rr) acc[rr] = bb;
#pragma unroll
  for (int k = 0; k < 48; k += 4) {
    float w0 = w[(k+0)*HDIM + hcol];
    float w1 = w[(k+1)*HDIM + hcol];
    float w2 = w[(k+2)*HDIM + hcol];
    float w3 = w[(k+3)*HDIM + hcol];
#pragma unroll
    for (int rr = 0; rr < 8; ++rr) {
      float4 xv = *(const float4*)&xs[rr][k];
      acc[rr] = fmaf(xv.x, w0, acc[rr]);
      acc[rr] = fmaf(xv.y, w1, acc[rr]);
      acc[rr] = fmaf(xv.z, w2, acc[rr]);
      acc[rr] = fmaf(xv.w, w3, acc[rr]);
    }
  }
#pragma unroll
  for (int k = 48; k < INDIM; ++k) {
    float wk = w[k*HDIM + hcol];
#pragma unroll
    for (int rr = 0; rr < 8; ++rr) acc[rr] = fmaf(xs[rr][k], wk, acc[rr]);
  }
#pragma unroll
  for (int rr = 0; rr < 8; ++rr) u[(size_t)(r0+rr)*HDIM + hcol] = acc[rr];
}

// ---------------- per-layer SSM coefficients: a=exp(dtA), Ct2=2*C*(a-1)/A
__global__ __launch_bounds__(256) void coef_kernel(
    const float* __restrict__ log_dt, const float* __restrict__ lAr,
    const float* __restrict__ Aim, const float* __restrict__ Cre,
    const float* __restrict__ Cim, float* __restrict__ coef) {
  int i = blockIdx.x*256 + threadIdx.x;  // h*64+n
  int h = i >> 6;
  float dt = expf(log_dt[h]);
  float Ar = -expf(lAr[i]);
  float Ai = Aim[i];
  float dr = Ar*dt, di = Ai*dt;
  float e = expf(dr);
  float are = e * cosf(di), aim = e * sinf(di);
  float inv = 1.f/(Ar*Ar + Ai*Ai);
  float nre = are - 1.f, nim = aim;
  float qre = (nre*Ar + nim*Ai)*inv;
  float qim = (nim*Ar - nre*Ai)*inv;
  float cre = Cre[i], cim = Cim[i];
  float Ctr = cre*qre - cim*qim;
  float Cti = cre*qim + cim*qre;
  coef[0*HN + i] = are;
  coef[1*HN + i] = aim;
  coef[2*HN + i] = 2.f*Ctr;
  coef[3*HN + i] = 2.f*Cti;
}

// ---------------- transpose u[B,L,H] -> ut[B,H,L]
__global__ void transpose_LH_HL(const float* __restrict__ in, float* __restrict__ out) {
  __shared__ float tile[32][33];
  int b = blockIdx.z, l0 = blockIdx.x*32, h0 = blockIdx.y*32;
  int tx = threadIdx.x, ty = threadIdx.y;  // (32,8)
#pragma unroll
  for (int i = 0; i < 32; i += 8)
    tile[ty+i][tx] = in[((size_t)b*LSEQ + l0+ty+i)*HDIM + h0+tx];
  __syncthreads();
#pragma unroll
  for (int i = 0; i < 32; i += 8)
    out[((size_t)b*HDIM + h0+ty+i)*LSEQ + l0+tx] = tile[tx][ty+i];
}

// ---------------- sequential diagonal-SSM scan: one wave per (b,h), lane = state n
// zt[b,h,l] = gelu( y + u*D ),  y_l = 2*Re(sum_n Ct_n s_l),  s_l = a s_{l-1} + u_l
__global__ __launch_bounds__(64) void scan_kernel(
    const float* __restrict__ ut, const float* __restrict__ coef,
    const float* __restrict__ Dv, float* __restrict__ zt) {
  const int bh = blockIdx.x;       // 0..2047
  const int h = bh & (HDIM-1);
  const int n = threadIdx.x;
  const float ar = coef[0*HN + h*NSTATE + n];
  const float ai = coef[1*HN + h*NSTATE + n];
  const float cr = coef[2*HN + h*NSTATE + n];
  const float ci = coef[3*HN + h*NSTATE + n];
  const float Dh = Dv[h];
  const float* urow = ut + (size_t)bh * LSEQ;
  float* zrow = zt + (size_t)bh * LSEQ;
  float sre = 0.f, sim = 0.f;
  for (int c = 0; c < LSEQ/64; ++c) {
    float uv = urow[c*64 + n];   // coalesced; lane t holds u_{c*64+t}
    float yacc = 0.f;
#pragma unroll
    for (int t = 0; t < 64; ++t) {
      float xv = rdlane(uv, t);
      float nsre = fmaf(ar, sre, fmaf(-ai, sim, xv));
      float nsim = fmaf(ar, sim, ai*sre);
      sre = nsre; sim = nsim;
      float contrib = fmaf(cr, sre, -(ci*sim));
      float tot = wave_sum64(contrib);      // lane 63
      float ys = rdlane(tot, 63);           // SGPR broadcast
      yacc = (n == t) ? ys : yacc;          // commit y_t to lane t
    }
    float pre = fmaf(uv, Dh, yacc);
    zrow[c*64 + n] = gelu_tanh(pre);
  }
}

// ---------------- GLU block: w = z @ W[256,512] + b; u += w[:, :256]*sigmoid(w[:,256:])
// z comes transposed: zt[b,h,l]
__global__ __launch_bounds__(256) void glu_kernel(
    const float* __restrict__ zt, const float* __restrict__ w,
    const float* __restrict__ bias, float* __restrict__ u) {
  __shared__ float As[32][132];
  __shared__ float Ba[32][68];
  __shared__ float Bg[32][68];
  const int r0 = blockIdx.x * 128;
  const int c0 = blockIdx.y * 64;
  const int b = r0 >> 11;        // /2048
  const int l0 = r0 & (LSEQ-1);
  const int tid = threadIdx.x;
  const int tm = tid >> 4, tn = tid & 15;
  float acc_a[8][4] = {};
  float acc_g[8][4] = {};
  for (int k0 = 0; k0 < HDIM; k0 += 32) {
#pragma unroll
    for (int p = 0; p < 4; ++p) {
      int lin = tid + p*256;            // 1024 float4 units
      int m4 = lin & 31, k = lin >> 5;
      float4 v = *(const float4*)&zt[((size_t)(b*HDIM + k0 + k))*LSEQ + l0 + m4*4];
      *(float4*)&As[k][m4*4] = v;
    }
#pragma unroll
    for (int p = 0; p < 2; ++p) {
      int lin = tid + p*256;            // 512 float4 units
      int n4 = lin & 15, k = lin >> 4;
      *(float4*)&Ba[k][n4*4] = *(const float4*)&w[(size_t)(k0+k)*512 + c0 + n4*4];
      *(float4*)&Bg[k][n4*4] = *(const float4*)&w[(size_t)(k0+k)*512 + 256 + c0 + n4*4];
    }
    __syncthreads();
#pragma unroll
    for (int k = 0; k < 32; ++k) {
      float4 a0 = *(const float4*)&As[k][tm*8];
      float4 a1 = *(const float4*)&As[k][tm*8+4];
      float4 bav = *(const float4*)&Ba[k][tn*4];
      float4 bgv = *(const float4*)&Bg[k][tn*4];
      float am[8] = {a0.x,a0.y,a0.z,a0.w,a1.x,a1.y,a1.z,a1.w};
      float bA[4] = {bav.x,bav.y,bav.z,bav.w};
      float bG[4] = {bgv.x,bgv.y,bgv.z,bgv.w};
#pragma unroll
      for (int i = 0; i < 8; ++i)
#pragma unroll
        for (int j = 0; j < 4; ++j) {
          acc_a[i][j] = fmaf(am[i], bA[j], acc_a[i][j]);
          acc_g[i][j] = fmaf(am[i], bG[j], acc_g[i][j]);
        }
    }
    __syncthreads();
  }
#pragma unroll
  for (int i = 0; i < 8; ++i) {
    int r = r0 + tm*8 + i;
    float4 res = *(const float4*)&u[(size_t)r*HDIM + c0 + tn*4];
    float rv[4] = {res.x,res.y,res.z,res.w};
    float o[4];
#pragma unroll
    for (int j = 0; j < 4; ++j) {
      int c = c0 + tn*4 + j;
      float wa = acc_a[i][j] + bias[c];
      float wg = acc_g[i][j] + bias[256 + c];
      float sig = 1.f/(1.f + expf(-wg));
      o[j] = rv[j] + wa*sig;
    }
    float4 ov = {o[0],o[1],o[2],o[3]};
    *(float4*)&u[(size_t)r*HDIM + c0 + tn*4] = ov;
  }
}

// ---------------- LayerNorm over H=256 per row -> un
__global__ __launch_bounds__(256) void ln_kernel(
    const float* __restrict__ u, const float* __restrict__ g,
    const float* __restrict__ b, float* __restrict__ un) {
  const int r0 = blockIdx.x * 8;
  const int w = threadIdx.x >> 6;
  const int lane = threadIdx.x & 63;
#pragma unroll
  for (int rr = 0; rr < 2; ++rr) {
    int r = r0 + w*2 + rr;
    float4 v = *(const float4*)&u[(size_t)r*HDIM + lane*4];
    float s = v.x+v.y+v.z+v.w;
    float sq = v.x*v.x + v.y*v.y + v.z*v.z + v.w*v.w;
    s = wave_sum64(s);
    sq = wave_sum64(sq);
    float mu = rdlane(s, 63) * (1.f/256.f);
    float ms = rdlane(sq, 63) * (1.f/256.f);
    float rstd = rsqrtf(ms - mu*mu + 1e-5f);
    float4 gg = *(const float4*)&g[lane*4];
    float4 bb = *(const float4*)&b[lane*4];
    float4 o;
    o.x = (v.x-mu)*rstd*gg.x + bb.x;
    o.y = (v.y-mu)*rstd*gg.y + bb.y;
    o.z = (v.z-mu)*rstd*gg.z + bb.z;
    o.w = (v.w-mu)*rstd*gg.w + bb.w;
    *(float4*)&un[(size_t)r*HDIM + lane*4] = o;
  }
}

// ---------------- head: un[16384,256] @ hw[256,204] + hb -> out
__global__ __launch_bounds__(256) void head_kernel(
    const float* __restrict__ un, const float* __restrict__ hw,
    const float* __restrict__ hb, float* __restrict__ out) {
  __shared__ float As[32][132];
  __shared__ float Bs[32][68];
  const int r0 = blockIdx.x * 128;
  const int c0 = blockIdx.y * 64;
  const int tid = threadIdx.x;
  const int tm = tid >> 4, tn = tid & 15;
  float acc[8][4] = {};
  for (int k0 = 0; k0 < HDIM; k0 += 32) {
#pragma unroll
    for (int p = 0; p < 16; ++p) {
      int lin = tid + p*256;       // 4096
      int k = lin & 31, m = lin >> 5;
      As[k][m] = un[(size_t)(r0+m)*HDIM + k0 + k];
    }
#pragma unroll
    for (int p = 0; p < 8; ++p) {
      int lin = tid + p*256;       // 2048
      int n = lin & 63, k = lin >> 6;
      int c = c0 + n;
      Bs[k][n] = (c < OUTC) ? hw[(size_t)(k0+k)*OUTC + c] : 0.f;
    }
    __syncthreads();
#pragma unroll
    for (int k = 0; k < 32; ++k) {
      float4 a0 = *(const float4*)&As[k][tm*8];
      float4 a1 = *(const float4*)&As[k][tm*8+4];
      float4 bv = *(const float4*)&Bs[k][tn*4];
      float am[8] = {a0.x,a0.y,a0.z,a0.w,a1.x,a1.y,a1.z,a1.w};
      float bb[4] = {bv.x,bv.y,bv.z,bv.w};
#pragma unroll
      for (int i = 0; i < 8; ++i)
#pragma unroll
        for (int j = 0; j < 4; ++j)
          acc[i][j] = fmaf(am[i], bb[j], acc[i][j]);
    }
    __syncthreads();
  }
#pragma unroll
  for (int i = 0; i < 8; ++i) {
    int r = r0 + tm*8 + i;
#pragma unroll
    for (int j = 0; j < 4; ++j) {
      int c = c0 + tn*4 + j;
      if (c < OUTC) out[(size_t)r*OUTC + c] = acc[i][j] + hb[c];
    }
  }
}

extern "C" void kernel_launch(void* const* d_in, const int* in_sizes, int n_in,
                              void* d_out, int out_size, void* d_ws, size_t ws_size,
                              hipStream_t stream) {
  const float* x       = (const float*)d_in[0];
  const float* proj_w  = (const float*)d_in[1];
  const float* proj_b  = (const float*)d_in[2];
  const float* log_dt  = (const float*)d_in[3];
  const float* lAr     = (const float*)d_in[4];
  const float* Aim     = (const float*)d_in[5];
  const float* Cre     = (const float*)d_in[6];
  const float* Cim     = (const float*)d_in[7];
  const float* Dp      = (const float*)d_in[8];
  const float* out_w   = (const float*)d_in[9];
  const float* out_b   = (const float*)d_in[10];
  const float* ln_g    = (const float*)d_in[11];
  const float* ln_b    = (const float*)d_in[12];
  const float* head_w  = (const float*)d_in[13];
  const float* head_b  = (const float*)d_in[14];
  float* outp = (float*)d_out;

  float* u    = (float*)d_ws;              // [16384,256]
  float* ut   = u  + (size_t)NROWS*HDIM;   // [B,H,L] transposed (also reused as un)
  float* zt   = ut + (size_t)NROWS*HDIM;   // [B,H,L]
  float* coef = zt + (size_t)NROWS*HDIM;   // [4][H*N]

  // input projection
  proj_kernel<<<NROWS/8, 256, 0, stream>>>(x, proj_w, proj_b, u);

  for (int d = 0; d < NDEPTH; ++d) {
    coef_kernel<<<HN/256, 256, 0, stream>>>(
        log_dt + d*HDIM, lAr + (size_t)d*HN, Aim + (size_t)d*HN,
        Cre + (size_t)d*HN, Cim + (size_t)d*HN, coef);
    dim3 tg(LSEQ/32, HDIM/32, NBATCH);
    transpose_LH_HL<<<tg, dim3(32,8), 0, stream>>>(u, ut);
    scan_kernel<<<NBATCH*HDIM, 64, 0, stream>>>(ut, coef, Dp + d*HDIM, zt);
    glu_kernel<<<dim3(NROWS/128, 4), 256, 0, stream>>>(
        zt, out_w + (size_t)d*HDIM*512, out_b + d*512, u);
  }

  ln_kernel<<<NROWS/8, 256, 0, stream>>>(u, ln_g, ln_b, ut);
  head_kernel<<<dim3(NROWS/128, 4), 256, 0, stream>>>(ut, head_w, head_b, outp);
}

// Round 3
// 660.216 us; speedup vs baseline: 1.5996x; 1.5996x over previous
//
#include <hip/hip_runtime.h>
#include <math.h>

#define HDIM 256
#define NSTATE 64
#define NDEPTH 4
#define LSEQ 2048
#define NBATCH 8
#define NROWS (NBATCH*LSEQ)   // 16384
#define HN (HDIM*NSTATE)      // 16384
#define INDIM 51
#define OUTC 204

// ---------------- cross-lane helpers (DPP, VALU pipe) ----------------
template<int CTRL>
__device__ __forceinline__ float dpp_add(float x) {
  int y = __builtin_amdgcn_update_dpp(0, __float_as_int(x), CTRL, 0xf, 0xf, true);
  return x + __int_as_float(y);
}
// full wave64 sum; total lands in lane 63
__device__ __forceinline__ float wave_sum64(float x) {
  x = dpp_add<0x111>(x);  // row_shr:1
  x = dpp_add<0x112>(x);  // row_shr:2
  x = dpp_add<0x114>(x);  // row_shr:4
  x = dpp_add<0x118>(x);  // row_shr:8
  x = dpp_add<0x142>(x);  // row_bcast:15
  x = dpp_add<0x143>(x);  // row_bcast:31
  return x;
}
__device__ __forceinline__ float rdlane(float v, int lane) {
  return __int_as_float(__builtin_amdgcn_readlane(__float_as_int(v), lane));
}
__device__ __forceinline__ float gelu_tanh(float x) {
  float x3 = x*x*x;
  return 0.5f*x*(1.f + tanhf(0.7978845608028654f*(x + 0.044715f*x3)));
}

// ---------------- input projection: x[16384,51] @ w[51,256] + b -> u[16384,256]
__global__ __launch_bounds__(256) void proj_kernel(
    const float* __restrict__ x, const float* __restrict__ w,
    const float* __restrict__ bias, float* __restrict__ u) {
  __shared__ float xs[8][52];  // padded rows, float4-aligned
  const int r0 = blockIdx.x * 8;
  const int tid = threadIdx.x;
  for (int idx = tid; idx < 8*INDIM; idx += 256) {
    int rr = idx / INDIM, k = idx % INDIM;
    xs[rr][k] = x[(size_t)(r0+rr)*INDIM + k];
  }
  __syncthreads();
  const int hcol = tid;
  float acc[8];
  const float bb = bias[hcol];
#pragma unroll
  for (int rr = 0; rr < 8; ++rr) acc[rr] = bb;
#pragma unroll
  for (int k = 0; k < 48; k += 4) {
    float w0 = w[(k+0)*HDIM + hcol];
    float w1 = w[(k+1)*HDIM + hcol];
    float w2 = w[(k+2)*HDIM + hcol];
    float w3 = w[(k+3)*HDIM + hcol];
#pragma unroll
    for (int rr = 0; rr < 8; ++rr) {
      float4 xv = *(const float4*)&xs[rr][k];
      acc[rr] = fmaf(xv.x, w0, acc[rr]);
      acc[rr] = fmaf(xv.y, w1, acc[rr]);
      acc[rr] = fmaf(xv.z, w2, acc[rr]);
      acc[rr] = fmaf(xv.w, w3, acc[rr]);
    }
  }
#pragma unroll
  for (int k = 48; k < INDIM; ++k) {
    float wk = w[k*HDIM + hcol];
#pragma unroll
    for (int rr = 0; rr < 8; ++rr) acc[rr] = fmaf(xs[rr][k], wk, acc[rr]);
  }
#pragma unroll
  for (int rr = 0; rr < 8; ++rr) u[(size_t)(r0+rr)*HDIM + hcol] = acc[rr];
}

// ---------------- per-layer SSM coefficients: a=exp(dtA), Ct2=2*C*(a-1)/A
__global__ __launch_bounds__(256) void coef_kernel(
    const float* __restrict__ log_dt, const float* __restrict__ lAr,
    const float* __restrict__ Aim, const float* __restrict__ Cre,
    const float* __restrict__ Cim, float* __restrict__ coef) {
  int i = blockIdx.x*256 + threadIdx.x;  // h*64+n
  int h = i >> 6;
  float dt = expf(log_dt[h]);
  float Ar = -expf(lAr[i]);
  float Ai = Aim[i];
  float dr = Ar*dt, di = Ai*dt;
  float e = expf(dr);
  float are = e * cosf(di), aim = e * sinf(di);
  float inv = 1.f/(Ar*Ar + Ai*Ai);
  float nre = are - 1.f, nim = aim;
  float qre = (nre*Ar + nim*Ai)*inv;
  float qim = (nim*Ar - nre*Ai)*inv;
  float cre = Cre[i], cim = Cim[i];
  float Ctr = cre*qre - cim*qim;
  float Cti = cre*qim + cim*qre;
  coef[0*HN + i] = are;
  coef[1*HN + i] = aim;
  coef[2*HN + i] = 2.f*Ctr;
  coef[3*HN + i] = 2.f*Cti;
}

// ---------------- transpose u[B,L,H] -> ut[B,H,L]
__global__ void transpose_LH_HL(const float* __restrict__ in, float* __restrict__ out) {
  __shared__ float tile[32][33];
  int b = blockIdx.z, l0 = blockIdx.x*32, h0 = blockIdx.y*32;
  int tx = threadIdx.x, ty = threadIdx.y;  // (32,8)
#pragma unroll
  for (int i = 0; i < 32; i += 8)
    tile[ty+i][tx] = in[((size_t)b*LSEQ + l0+ty+i)*HDIM + h0+tx];
  __syncthreads();
#pragma unroll
  for (int i = 0; i < 32; i += 8)
    out[((size_t)b*HDIM + h0+ty+i)*LSEQ + l0+tx] = tile[tx][ty+i];
}

// ---------------- chunk-parallel diagonal-SSM scan
// One block per (b,h). L=2048 split into 32 chunks of T=64.
// y_t = conv(k,u)_t + 2Re(sum_n a^{t+1} Ct_n s_init_n); k_m = 2Re(sum_n Ct_n a^m)
__global__ __launch_bounds__(256) void scan_kernel(
    const float* __restrict__ ut, const float* __restrict__ coef,
    const float* __restrict__ Dv, float* __restrict__ zt) {
  __shared__ float EC[64*130];   // E[n][t] complex interleaved: EC[n*130+2t]=Re, +1=Im
  __shared__ float Sre[32*64];   // per-chunk local state -> then s_init
  __shared__ float Sim[32*64];
  __shared__ float kext[128];    // kext[0..63]=0, kext[64+m]=k_m
  const int bh = blockIdx.x;
  const int h = bh & (HDIM-1);
  const int tid = threadIdx.x;
  const int wid = tid >> 6;
  const int lane = tid & 63;
  const float ar = coef[0*HN + h*NSTATE + lane];
  const float ai = coef[1*HN + h*NSTATE + lane];
  const float cr = coef[2*HN + h*NSTATE + lane];  // 2*Ct re
  const float ci = coef[3*HN + h*NSTATE + lane];  // 2*Ct im
  const float Dh = Dv[h];
  const float* __restrict__ urow = ut + (size_t)bh * LSEQ;
  float* __restrict__ zrow = zt + (size_t)bh * LSEQ;

  if (tid < 64) kext[tid] = 0.f;

  // ---- E matrix: E[n][t] = a_n^{t+1}; wave w computes t in [16w, 16w+16)
  float a2r = fmaf(ar,ar,-ai*ai),     a2i = 2.f*ar*ai;
  float a4r = fmaf(a2r,a2r,-a2i*a2i), a4i = 2.f*a2r*a2i;
  float a8r = fmaf(a4r,a4r,-a4i*a4i), a8i = 2.f*a4r*a4i;
  float a16r= fmaf(a8r,a8r,-a8i*a8i), a16i= 2.f*a8r*a8i;
  float pr = 1.f, pi = 0.f;
  for (int i = 0; i < wid; ++i) {
    float nr = fmaf(pr,a16r,-pi*a16i);
    float ni = fmaf(pr,a16i, pi*a16r);
    pr = nr; pi = ni;
  }
  float er = fmaf(pr,ar,-pi*ai);   // a^{16w+1}
  float ei = fmaf(pr,ai, pi*ar);
  for (int t = wid*16; t < wid*16+16; ++t) {
    *(float2*)&EC[lane*130 + 2*t] = make_float2(er, ei);
    float nr = fmaf(er,ar,-ei*ai);
    float ni = fmaf(er,ai, ei*ar);
    er = nr; ei = ni;
  }

  // ---- Phase A: local chunk-end states (lane = n, 8 chunks per wave, interleaved)
  float uv[8], sre[8], sim[8];
#pragma unroll
  for (int cc = 0; cc < 8; ++cc) {
    uv[cc] = urow[(wid*8+cc)*64 + lane];
    sre[cc] = 0.f; sim[cc] = 0.f;
  }
  for (int j = 0; j < 64; ++j) {
#pragma unroll
    for (int cc = 0; cc < 8; ++cc) {
      float xv = rdlane(uv[cc], j);
      float nr = fmaf(ar, sre[cc], fmaf(-ai, sim[cc], xv));
      float ni = fmaf(ar, sim[cc], ai*sre[cc]);
      sre[cc] = nr; sim[cc] = ni;
    }
  }
#pragma unroll
  for (int cc = 0; cc < 8; ++cc) {
    Sre[(wid*8+cc)*64 + lane] = sre[cc];
    Sim[(wid*8+cc)*64 + lane] = sim[cc];
  }
  __syncthreads();

  // ---- Phase B (wave 0): sequential chunk-state combine; waves 1-3: kernel k
  if (wid == 0) {
    float a32r = fmaf(a16r,a16r,-a16i*a16i), a32i = 2.f*a16r*a16i;
    float a64r = fmaf(a32r,a32r,-a32i*a32i), a64i = 2.f*a32r*a32i;
    float rr = 0.f, ri = 0.f;
    for (int c = 0; c < 32; ++c) {
      float tre = Sre[c*64+lane], tim = Sim[c*64+lane];
      Sre[c*64+lane] = rr; Sim[c*64+lane] = ri;   // s_init for chunk c
      float nr = fmaf(a64r, rr, fmaf(-a64i, ri, tre));
      float ni = fmaf(a64r, ri, fmaf(a64i, rr, tim));
      rr = nr; ri = ni;
    }
  } else {
    int m0 = (wid-1)*22;
    int m1 = (wid==3) ? 64 : (m0+22);
    for (int m = m0; m < m1; ++m) {
      float v;
      if (m == 0) {
        v = cr;
      } else {
        float2 ev = *(const float2*)&EC[lane*130 + 2*(m-1)];
        v = fmaf(cr, ev.x, -ci*ev.y);
      }
      v = wave_sum64(v);
      if (lane == 63) kext[64+m] = v;
    }
  }
  __syncthreads();

  // ---- Phase C: per chunk output (lane = t within chunk)
  for (int cc = 0; cc < 8; ++cc) {
    int c = wid*8 + cc;
    float uvc = urow[c*64 + lane];
    float sir = Sre[c*64+lane], sii = Sim[c*64+lane];   // s_init (lane as n)
    float wr = fmaf(cr, sir, -ci*sii);                  // w = 2Ct * s_init
    float wi = fmaf(cr, sii,  ci*sir);
    float accv[4] = {0.f,0.f,0.f,0.f};
    // correction: sum_n Re(E[n][t] * w[n])
    for (int n4 = 0; n4 < 64; n4 += 4) {
#pragma unroll
      for (int k = 0; k < 4; ++k) {
        int n = n4 + k;
        float2 ev = *(const float2*)&EC[n*130 + 2*lane];
        accv[k] = fmaf(rdlane(wr,n), ev.x, accv[k]);
        accv[k] = fmaf(-rdlane(wi,n), ev.y, accv[k]);
      }
    }
    // causal conv: sum_{j<=t} k_{t-j} u_j
    for (int j4 = 0; j4 < 64; j4 += 4) {
#pragma unroll
      for (int k = 0; k < 4; ++k) {
        int j = j4 + k;
        accv[k] = fmaf(rdlane(uvc,j), kext[64 + lane - j], accv[k]);
      }
    }
    float acc = (accv[0]+accv[1]) + (accv[2]+accv[3]);
    float pre = fmaf(uvc, Dh, acc);
    zrow[c*64+lane] = gelu_tanh(pre);
  }
}

// ---------------- GLU block: w = z @ W[256,512] + b; u += w[:, :256]*sigmoid(w[:,256:])
// z comes transposed: zt[b,h,l]
__global__ __launch_bounds__(256) void glu_kernel(
    const float* __restrict__ zt, const float* __restrict__ w,
    const float* __restrict__ bias, float* __restrict__ u) {
  __shared__ float As[32][132];
  __shared__ float Ba[32][68];
  __shared__ float Bg[32][68];
  const int r0 = blockIdx.x * 128;
  const int c0 = blockIdx.y * 64;
  const int b = r0 >> 11;        // /2048
  const int l0 = r0 & (LSEQ-1);
  const int tid = threadIdx.x;
  const int tm = tid >> 4, tn = tid & 15;
  float acc_a[8][4] = {};
  float acc_g[8][4] = {};
  for (int k0 = 0; k0 < HDIM; k0 += 32) {
#pragma unroll
    for (int p = 0; p < 4; ++p) {
      int lin = tid + p*256;            // 1024 float4 units
      int m4 = lin & 31, k = lin >> 5;
      float4 v = *(const float4*)&zt[((size_t)(b*HDIM + k0 + k))*LSEQ + l0 + m4*4];
      *(float4*)&As[k][m4*4] = v;
    }
#pragma unroll
    for (int p = 0; p < 2; ++p) {
      int lin = tid + p*256;            // 512 float4 units
      int n4 = lin & 15, k = lin >> 4;
      *(float4*)&Ba[k][n4*4] = *(const float4*)&w[(size_t)(k0+k)*512 + c0 + n4*4];
      *(float4*)&Bg[k][n4*4] = *(const float4*)&w[(size_t)(k0+k)*512 + 256 + c0 + n4*4];
    }
    __syncthreads();
#pragma unroll
    for (int k = 0; k < 32; ++k) {
      float4 a0 = *(const float4*)&As[k][tm*8];
      float4 a1 = *(const float4*)&As[k][tm*8+4];
      float4 bav = *(const float4*)&Ba[k][tn*4];
      float4 bgv = *(const float4*)&Bg[k][tn*4];
      float am[8] = {a0.x,a0.y,a0.z,a0.w,a1.x,a1.y,a1.z,a1.w};
      float bA[4] = {bav.x,bav.y,bav.z,bav.w};
      float bG[4] = {bgv.x,bgv.y,bgv.z,bgv.w};
#pragma unroll
      for (int i = 0; i < 8; ++i)
#pragma unroll
        for (int j = 0; j < 4; ++j) {
          acc_a[i][j] = fmaf(am[i], bA[j], acc_a[i][j]);
          acc_g[i][j] = fmaf(am[i], bG[j], acc_g[i][j]);
        }
    }
    __syncthreads();
  }
#pragma unroll
  for (int i = 0; i < 8; ++i) {
    int r = r0 + tm*8 + i;
    float4 res = *(const float4*)&u[(size_t)r*HDIM + c0 + tn*4];
    float rv[4] = {res.x,res.y,res.z,res.w};
    float o[4];
#pragma unroll
    for (int j = 0; j < 4; ++j) {
      int c = c0 + tn*4 + j;
      float wa = acc_a[i][j] + bias[c];
      float wg = acc_g[i][j] + bias[256 + c];
      float sig = 1.f/(1.f + expf(-wg));
      o[j] = rv[j] + wa*sig;
    }
    float4 ov = {o[0],o[1],o[2],o[3]};
    *(float4*)&u[(size_t)r*HDIM + c0 + tn*4] = ov;
  }
}

// ---------------- LayerNorm over H=256 per row -> un
__global__ __launch_bounds__(256) void ln_kernel(
    const float* __restrict__ u, const float* __restrict__ g,
    const float* __restrict__ b, float* __restrict__ un) {
  const int r0 = blockIdx.x * 8;
  const int w = threadIdx.x >> 6;
  const int lane = threadIdx.x & 63;
#pragma unroll
  for (int rr = 0; rr < 2; ++rr) {
    int r = r0 + w*2 + rr;
    float4 v = *(const float4*)&u[(size_t)r*HDIM + lane*4];
    float s = v.x+v.y+v.z+v.w;
    float sq = v.x*v.x + v.y*v.y + v.z*v.z + v.w*v.w;
    s = wave_sum64(s);
    sq = wave_sum64(sq);
    float mu = rdlane(s, 63) * (1.f/256.f);
    float ms = rdlane(sq, 63) * (1.f/256.f);
    float rstd = rsqrtf(ms - mu*mu + 1e-5f);
    float4 gg = *(const float4*)&g[lane*4];
    float4 bb = *(const float4*)&b[lane*4];
    float4 o;
    o.x = (v.x-mu)*rstd*gg.x + bb.x;
    o.y = (v.y-mu)*rstd*gg.y + bb.y;
    o.z = (v.z-mu)*rstd*gg.z + bb.z;
    o.w = (v.w-mu)*rstd*gg.w + bb.w;
    *(float4*)&un[(size_t)r*HDIM + lane*4] = o;
  }
}

// ---------------- head: un[16384,256] @ hw[256,204] + hb -> out
__global__ __launch_bounds__(256) void head_kernel(
    const float* __restrict__ un, const float* __restrict__ hw,
    const float* __restrict__ hb, float* __restrict__ out) {
  __shared__ float As[32][132];
  __shared__ float Bs[32][68];
  const int r0 = blockIdx.x * 128;
  const int c0 = blockIdx.y * 64;
  const int tid = threadIdx.x;
  const int tm = tid >> 4, tn = tid & 15;
  float acc[8][4] = {};
  for (int k0 = 0; k0 < HDIM; k0 += 32) {
#pragma unroll
    for (int p = 0; p < 16; ++p) {
      int lin = tid + p*256;       // 4096
      int k = lin & 31, m = lin >> 5;
      As[k][m] = un[(size_t)(r0+m)*HDIM + k0 + k];
    }
#pragma unroll
    for (int p = 0; p < 8; ++p) {
      int lin = tid + p*256;       // 2048
      int n = lin & 63, k = lin >> 6;
      int c = c0 + n;
      Bs[k][n] = (c < OUTC) ? hw[(size_t)(k0+k)*OUTC + c] : 0.f;
    }
    __syncthreads();
#pragma unroll
    for (int k = 0; k < 32; ++k) {
      float4 a0 = *(const float4*)&As[k][tm*8];
      float4 a1 = *(const float4*)&As[k][tm*8+4];
      float4 bv = *(const float4*)&Bs[k][tn*4];
      float am[8] = {a0.x,a0.y,a0.z,a0.w,a1.x,a1.y,a1.z,a1.w};
      float bb[4] = {bv.x,bv.y,bv.z,bv.w};
#pragma unroll
      for (int i = 0; i < 8; ++i)
#pragma unroll
        for (int j = 0; j < 4; ++j)
          acc[i][j] = fmaf(am[i], bb[j], acc[i][j]);
    }
    __syncthreads();
  }
#pragma unroll
  for (int i = 0; i < 8; ++i) {
    int r = r0 + tm*8 + i;
#pragma unroll
    for (int j = 0; j < 4; ++j) {
      int c = c0 + tn*4 + j;
      if (c < OUTC) out[(size_t)r*OUTC + c] = acc[i][j] + hb[c];
    }
  }
}

extern "C" void kernel_launch(void* const* d_in, const int* in_sizes, int n_in,
                              void* d_out, int out_size, void* d_ws, size_t ws_size,
                              hipStream_t stream) {
  const float* x       = (const float*)d_in[0];
  const float* proj_w  = (const float*)d_in[1];
  const float* proj_b  = (const float*)d_in[2];
  const float* log_dt  = (const float*)d_in[3];
  const float* lAr     = (const float*)d_in[4];
  const float* Aim     = (const float*)d_in[5];
  const float* Cre     = (const float*)d_in[6];
  const float* Cim     = (const float*)d_in[7];
  const float* Dp      = (const float*)d_in[8];
  const float* out_w   = (const float*)d_in[9];
  const float* out_b   = (const float*)d_in[10];
  const float* ln_g    = (const float*)d_in[11];
  const float* ln_b    = (const float*)d_in[12];
  const float* head_w  = (const float*)d_in[13];
  const float* head_b  = (const float*)d_in[14];
  float* outp = (float*)d_out;

  float* u    = (float*)d_ws;              // [16384,256]
  float* ut   = u  + (size_t)NROWS*HDIM;   // [B,H,L] transposed (also reused as un)
  float* zt   = ut + (size_t)NROWS*HDIM;   // [B,H,L]
  float* coef = zt + (size_t)NROWS*HDIM;   // [4][H*N]

  // input projection
  proj_kernel<<<NROWS/8, 256, 0, stream>>>(x, proj_w, proj_b, u);

  for (int d = 0; d < NDEPTH; ++d) {
    coef_kernel<<<HN/256, 256, 0, stream>>>(
        log_dt + d*HDIM, lAr + (size_t)d*HN, Aim + (size_t)d*HN,
        Cre + (size_t)d*HN, Cim + (size_t)d*HN, coef);
    dim3 tg(LSEQ/32, HDIM/32, NBATCH);
    transpose_LH_HL<<<tg, dim3(32,8), 0, stream>>>(u, ut);
    scan_kernel<<<NBATCH*HDIM, 256, 0, stream>>>(ut, coef, Dp + d*HDIM, zt);
    glu_kernel<<<dim3(NROWS/128, 4), 256, 0, stream>>>(
        zt, out_w + (size_t)d*HDIM*512, out_b + d*512, u);
  }

  ln_kernel<<<NROWS/8, 256, 0, stream>>>(u, ln_g, ln_b, ut);
  head_kernel<<<dim3(NROWS/128, 4), 256, 0, stream>>>(ut, head_w, head_b, outp);
}

// Round 4
// 500.985 us; speedup vs baseline: 2.1080x; 1.3178x over previous
//
#include <hip/hip_runtime.h>
#include <math.h>

#define HDIM 256
#define NSTATE 64
#define NDEPTH 4
#define LSEQ 2048
#define NBATCH 8
#define NROWS (NBATCH*LSEQ)   // 16384
#define HN (HDIM*NSTATE)      // 16384
#define INDIM 51
#define OUTC 204

typedef short bfrag8 __attribute__((ext_vector_type(8)));
typedef float facc4 __attribute__((ext_vector_type(4)));

// ---------------- cross-lane helpers (DPP, VALU pipe) ----------------
template<int CTRL>
__device__ __forceinline__ float dpp_add(float x) {
  int y = __builtin_amdgcn_update_dpp(0, __float_as_int(x), CTRL, 0xf, 0xf, true);
  return x + __int_as_float(y);
}
__device__ __forceinline__ float wave_sum64(float x) {
  x = dpp_add<0x111>(x);
  x = dpp_add<0x112>(x);
  x = dpp_add<0x114>(x);
  x = dpp_add<0x118>(x);
  x = dpp_add<0x142>(x);
  x = dpp_add<0x143>(x);
  return x;   // total in lane 63
}
__device__ __forceinline__ float rdlane(float v, int lane) {
  return __int_as_float(__builtin_amdgcn_readlane(__float_as_int(v), lane));
}
__device__ __forceinline__ float gelu_tanh(float x) {
  float x3 = x*x*x;
  return 0.5f*x*(1.f + tanhf(0.7978845608028654f*(x + 0.044715f*x3)));
}
__device__ __forceinline__ unsigned short f2bf(float x) {
  unsigned u = __float_as_uint(x);
  unsigned r = (u + 0x7FFFu + ((u >> 16) & 1u)) >> 16;
  return (unsigned short)r;
}
__device__ __forceinline__ float bf2f(unsigned short h) {
  return __uint_as_float(((unsigned)h) << 16);
}

// ---------------- input projection: x[16384,51] @ w[51,256] + b -> u[16384,256]
__global__ __launch_bounds__(256) void proj_kernel(
    const float* __restrict__ x, const float* __restrict__ w,
    const float* __restrict__ bias, float* __restrict__ u) {
  __shared__ float xs[8][52];
  const int r0 = blockIdx.x * 8;
  const int tid = threadIdx.x;
  for (int idx = tid; idx < 8*INDIM; idx += 256) {
    int rr = idx / INDIM, k = idx % INDIM;
    xs[rr][k] = x[(size_t)(r0+rr)*INDIM + k];
  }
  __syncthreads();
  const int hcol = tid;
  float acc[8];
  const float bb = bias[hcol];
#pragma unroll
  for (int rr = 0; rr < 8; ++rr) acc[rr] = bb;
#pragma unroll
  for (int k = 0; k < 48; k += 4) {
    float w0 = w[(k+0)*HDIM + hcol];
    float w1 = w[(k+1)*HDIM + hcol];
    float w2 = w[(k+2)*HDIM + hcol];
    float w3 = w[(k+3)*HDIM + hcol];
#pragma unroll
    for (int rr = 0; rr < 8; ++rr) {
      float4 xv = *(const float4*)&xs[rr][k];
      acc[rr] = fmaf(xv.x, w0, acc[rr]);
      acc[rr] = fmaf(xv.y, w1, acc[rr]);
      acc[rr] = fmaf(xv.z, w2, acc[rr]);
      acc[rr] = fmaf(xv.w, w3, acc[rr]);
    }
  }
#pragma unroll
  for (int k = 48; k < INDIM; ++k) {
    float wk = w[k*HDIM + hcol];
#pragma unroll
    for (int rr = 0; rr < 8; ++rr) acc[rr] = fmaf(xs[rr][k], wk, acc[rr]);
  }
#pragma unroll
  for (int rr = 0; rr < 8; ++rr) u[(size_t)(r0+rr)*HDIM + hcol] = acc[rr];
}

// ---------------- per-layer SSM coefficients: a=exp(dtA), Ct2=2*C*(a-1)/A
__global__ __launch_bounds__(256) void coef_kernel(
    const float* __restrict__ log_dt, const float* __restrict__ lAr,
    const float* __restrict__ Aim, const float* __restrict__ Cre,
    const float* __restrict__ Cim, float* __restrict__ coef) {
  int i = blockIdx.x*256 + threadIdx.x;
  int h = i >> 6;
  float dt = expf(log_dt[h]);
  float Ar = -expf(lAr[i]);
  float Ai = Aim[i];
  float dr = Ar*dt, di = Ai*dt;
  float e = expf(dr);
  float are = e * cosf(di), aim = e * sinf(di);
  float inv = 1.f/(Ar*Ar + Ai*Ai);
  float nre = are - 1.f, nim = aim;
  float qre = (nre*Ar + nim*Ai)*inv;
  float qim = (nim*Ar - nre*Ai)*inv;
  float cre = Cre[i], cim = Cim[i];
  float Ctr = cre*qre - cim*qim;
  float Cti = cre*qim + cim*qre;
  coef[0*HN + i] = are;
  coef[1*HN + i] = aim;
  coef[2*HN + i] = 2.f*Ctr;
  coef[3*HN + i] = 2.f*Cti;
}

// ---------------- transpose u[B,L,H] -> ut[B,H,L]
__global__ void transpose_LH_HL(const float* __restrict__ in, float* __restrict__ out) {
  __shared__ float tile[32][33];
  int b = blockIdx.z, l0 = blockIdx.x*32, h0 = blockIdx.y*32;
  int tx = threadIdx.x, ty = threadIdx.y;
#pragma unroll
  for (int i = 0; i < 32; i += 8)
    tile[ty+i][tx] = in[((size_t)b*LSEQ + l0+ty+i)*HDIM + h0+tx];
  __syncthreads();
#pragma unroll
  for (int i = 0; i < 32; i += 8)
    out[((size_t)b*HDIM + h0+ty+i)*LSEQ + l0+tx] = tile[tx][ty+i];
}

// ---------------- MFMA chunk-parallel scan
// Block = (h, batch-pair). cols = 32 chunks x 2 batches = 64. chunk T=64.
// GEMM-A: s_end[col][n] = sum_j u[col][j]*E2[n][j],  E2[n][j]=a_n^{63-j}
// combine: s_init serial over chunks; w = 2Ct*s_init
// GEMM-B: y[col][t] += Re(sum_n w[col][n]*a_n^{t+1})  (Epow_im stored negated)
// GEMM-C: y[col][t] += sum_j u[col][j]*k[t-j]
// all operands split hi/lo bf16 (3 mfma terms -> ~fp32 accuracy)
#define PADJ 72
#define MATSZ (64*PADJ)

__global__ __launch_bounds__(256) void scan_mfma(
    const float* __restrict__ ut, const float* __restrict__ coef,
    const float* __restrict__ Dv, float* __restrict__ zt) {
  __shared__ __align__(16) unsigned short EREG[4*MATSZ];  // E2 splits -> w splits -> T splits
  __shared__ __align__(16) float SREG[9216];              // s_end re/im -> Epow splits
  __shared__ __align__(16) unsigned short UREG[2*MATSZ];  // uh, ul
  __shared__ float kv[64];

  const int h  = blockIdx.x;
  const int bp = blockIdx.y;
  const int tid = threadIdx.x;
  const int w   = tid >> 6;
  const int l   = tid & 63;

  const float ar = coef[0*HN + h*64 + l];
  const float ai = coef[1*HN + h*64 + l];
  const float cr = coef[2*HN + h*64 + l];   // 2*Ct
  const float ci = coef[3*HN + h*64 + l];
  const float Dh = Dv[h];

  // powers of a (per lane n)
  float a2r = ar*ar - ai*ai,     a2i = 2.f*ar*ai;
  float a4r = a2r*a2r - a2i*a2i, a4i = 2.f*a2r*a2i;
  float a8r = a4r*a4r - a4i*a4i, a8i = 2.f*a4r*a4i;
  float a16r= a8r*a8r - a8i*a8i, a16i= 2.f*a8r*a8i;
  float a32r= a16r*a16r - a16i*a16i, a32i = 2.f*a16r*a16i;
  float a48r= a32r*a16r - a32i*a16i, a48i = a32r*a16i + a32i*a16r;
  float a64r= a32r*a32r - a32i*a32i, a64i = 2.f*a32r*a32i;

  unsigned short* e2rh = EREG;
  unsigned short* e2rl = EREG + MATSZ;
  unsigned short* e2ih = EREG + 2*MATSZ;
  unsigned short* e2il = EREG + 3*MATSZ;

  // ---- build E2[n][j] = a^{63-j}, wave w covers j in [16w,16w+16)
  {
    float pr, pi;  // a^{48-16w}
    if      (w == 3) { pr = 1.f;  pi = 0.f;  }
    else if (w == 2) { pr = a16r; pi = a16i; }
    else if (w == 1) { pr = a32r; pi = a32i; }
    else             { pr = a48r; pi = a48i; }
    for (int j = 16*w+15; j >= 16*w; --j) {
      int idx = l*PADJ + j;
      unsigned short hh = f2bf(pr);
      e2rh[idx] = hh; e2rl[idx] = f2bf(pr - bf2f(hh));
      hh = f2bf(pi);
      e2ih[idx] = hh; e2il[idx] = f2bf(pi - bf2f(hh));
      float nr = pr*ar - pi*ai, ni = pr*ai + pi*ar;
      pr = nr; pi = ni;
    }
  }

  // ---- stage u -> split bf16 [col][j]
  {
    unsigned short* uh = UREG;
    unsigned short* ul = UREG + MATSZ;
    const int bi = tid >> 7;
    const int b  = 2*bp + bi;
    const int l0 = (tid & 127) * 16;
    const float* src = ut + ((size_t)(b*HDIM + h))*LSEQ + l0;
    const int col = (bi << 5) + (l0 >> 6);
    const int j0  = l0 & 63;
#pragma unroll
    for (int i = 0; i < 16; i += 4) {
      float4 v = *(const float4*)&src[i];
      float vv[4] = {v.x, v.y, v.z, v.w};
#pragma unroll
      for (int q = 0; q < 4; ++q) {
        unsigned short hh = f2bf(vv[q]);
        uh[col*PADJ + j0 + i + q] = hh;
        ul[col*PADJ + j0 + i + q] = f2bf(vv[q] - bf2f(hh));
      }
    }
  }
  __syncthreads();

  float* s_re = SREG;            // [64][66]
  float* s_im = SREG + 64*66;

  // ---- GEMM-A: s_end[col][n]
  {
    const unsigned short* uh = UREG;
    const unsigned short* ul = UREG + MATSZ;
    facc4 accre[4], accim[4];
#pragma unroll
    for (int mt = 0; mt < 4; ++mt) { accre[mt] = (facc4){0.f,0.f,0.f,0.f}; accim[mt] = (facc4){0.f,0.f,0.f,0.f}; }
#pragma unroll
    for (int k0 = 0; k0 < 64; k0 += 32) {
      const int koff = k0 + 8*(l >> 4);
      const int brow = 16*w + (l & 15);
      bfrag8 brh = *(const bfrag8*)&e2rh[brow*PADJ + koff];
      bfrag8 brl = *(const bfrag8*)&e2rl[brow*PADJ + koff];
      bfrag8 bih = *(const bfrag8*)&e2ih[brow*PADJ + koff];
      bfrag8 bil = *(const bfrag8*)&e2il[brow*PADJ + koff];
#pragma unroll
      for (int mt = 0; mt < 4; ++mt) {
        const int arow = 16*mt + (l & 15);
        bfrag8 ah = *(const bfrag8*)&uh[arow*PADJ + koff];
        bfrag8 al = *(const bfrag8*)&ul[arow*PADJ + koff];
        accre[mt] = __builtin_amdgcn_mfma_f32_16x16x32_bf16(ah, brh, accre[mt], 0, 0, 0);
        accre[mt] = __builtin_amdgcn_mfma_f32_16x16x32_bf16(al, brh, accre[mt], 0, 0, 0);
        accre[mt] = __builtin_amdgcn_mfma_f32_16x16x32_bf16(ah, brl, accre[mt], 0, 0, 0);
        accim[mt] = __builtin_amdgcn_mfma_f32_16x16x32_bf16(ah, bih, accim[mt], 0, 0, 0);
        accim[mt] = __builtin_amdgcn_mfma_f32_16x16x32_bf16(al, bih, accim[mt], 0, 0, 0);
        accim[mt] = __builtin_amdgcn_mfma_f32_16x16x32_bf16(ah, bil, accim[mt], 0, 0, 0);
      }
    }
#pragma unroll
    for (int mt = 0; mt < 4; ++mt)
#pragma unroll
      for (int r = 0; r < 4; ++r) {
        int colg = 16*mt + 4*(l >> 4) + r;
        int ng   = 16*w + (l & 15);
        s_re[colg*66 + ng] = accre[mt][r];
        s_im[colg*66 + ng] = accim[mt][r];
      }
  }
  __syncthreads();

  // ---- combine (waves 0,1) + kernel k (waves 2,3)
  if (tid < 128) {
    unsigned short* wrh = EREG;
    unsigned short* wrl = EREG + MATSZ;
    unsigned short* wih = EREG + 2*MATSZ;
    unsigned short* wil = EREG + 3*MATSZ;
    const int n = l, bi = w;
    float rr = 0.f, ri = 0.f;
    for (int c = 0; c < 32; ++c) {
      int col = (bi << 5) + c;
      float tre = s_re[col*66 + n], tim = s_im[col*66 + n];
      float wre = cr*rr - ci*ri;
      float wim = cr*ri + ci*rr;
      unsigned short hh = f2bf(wre);
      wrh[col*PADJ + n] = hh; wrl[col*PADJ + n] = f2bf(wre - bf2f(hh));
      hh = f2bf(wim);
      wih[col*PADJ + n] = hh; wil[col*PADJ + n] = f2bf(wim - bf2f(hh));
      float nr = a64r*rr - a64i*ri + tre;
      float ni = a64r*ri + a64i*rr + tim;
      rr = nr; ri = ni;
    }
  } else {
    // k_m = Re(sum_n 2Ct_n a_n^m)
    float pr, pi;
    int m0;
    if (w == 2) { pr = cr; pi = ci; m0 = 0; }
    else        { pr = cr*a32r - ci*a32i; pi = cr*a32i + ci*a32r; m0 = 32; }
    for (int m = m0; m < m0 + 32; ++m) {
      float s = wave_sum64(pr);
      if (l == 63) kv[m] = s;
      float nr = pr*ar - pi*ai, ni = pr*ai + pi*ar;
      pr = nr; pi = ni;
    }
  }
  __syncthreads();

  // ---- build Epow[t][n] = a^{t+1} (im negated), into SREG as shorts
  unsigned short* eprh = (unsigned short*)SREG;
  unsigned short* eprl = eprh + MATSZ;
  unsigned short* epih = eprh + 2*MATSZ;
  unsigned short* epil = eprh + 3*MATSZ;
  {
    float pr, pi;  // a^{16w+1}
    if      (w == 0) { pr = ar; pi = ai; }
    else if (w == 1) { pr = a16r*ar - a16i*ai; pi = a16r*ai + a16i*ar; }
    else if (w == 2) { pr = a32r*ar - a32i*ai; pi = a32r*ai + a32i*ar; }
    else             { pr = a48r*ar - a48i*ai; pi = a48r*ai + a48i*ar; }
    for (int t = 16*w; t < 16*w + 16; ++t) {
      int idx = t*PADJ + l;
      unsigned short hh = f2bf(pr);
      eprh[idx] = hh; eprl[idx] = f2bf(pr - bf2f(hh));
      float nim = -pi;
      hh = f2bf(nim);
      epih[idx] = hh; epil[idx] = f2bf(nim - bf2f(hh));
      float nr = pr*ar - pi*ai, ni = pr*ai + pi*ar;
      pr = nr; pi = ni;
    }
  }
  __syncthreads();

  // ---- GEMM-B: y[col][t] += wre*Ere + wim*(-Eim)
  facc4 acc[4];
#pragma unroll
  for (int mt = 0; mt < 4; ++mt) acc[mt] = (facc4){0.f,0.f,0.f,0.f};
  {
    const unsigned short* wrh = EREG;
    const unsigned short* wrl = EREG + MATSZ;
    const unsigned short* wih = EREG + 2*MATSZ;
    const unsigned short* wil = EREG + 3*MATSZ;
#pragma unroll
    for (int k0 = 0; k0 < 64; k0 += 32) {
      const int koff = k0 + 8*(l >> 4);
      const int trow = 16*w + (l & 15);
      bfrag8 berh = *(const bfrag8*)&eprh[trow*PADJ + koff];
      bfrag8 berl = *(const bfrag8*)&eprl[trow*PADJ + koff];
      bfrag8 beih = *(const bfrag8*)&epih[trow*PADJ + koff];
      bfrag8 beil = *(const bfrag8*)&epil[trow*PADJ + koff];
#pragma unroll
      for (int mt = 0; mt < 4; ++mt) {
        const int arow = 16*mt + (l & 15);
        bfrag8 awrh = *(const bfrag8*)&wrh[arow*PADJ + koff];
        bfrag8 awrl = *(const bfrag8*)&wrl[arow*PADJ + koff];
        bfrag8 awih = *(const bfrag8*)&wih[arow*PADJ + koff];
        bfrag8 awil = *(const bfrag8*)&wil[arow*PADJ + koff];
        acc[mt] = __builtin_amdgcn_mfma_f32_16x16x32_bf16(awrh, berh, acc[mt], 0, 0, 0);
        acc[mt] = __builtin_amdgcn_mfma_f32_16x16x32_bf16(awrl, berh, acc[mt], 0, 0, 0);
        acc[mt] = __builtin_amdgcn_mfma_f32_16x16x32_bf16(awrh, berl, acc[mt], 0, 0, 0);
        acc[mt] = __builtin_amdgcn_mfma_f32_16x16x32_bf16(awih, beih, acc[mt], 0, 0, 0);
        acc[mt] = __builtin_amdgcn_mfma_f32_16x16x32_bf16(awil, beih, acc[mt], 0, 0, 0);
        acc[mt] = __builtin_amdgcn_mfma_f32_16x16x32_bf16(awih, beil, acc[mt], 0, 0, 0);
      }
    }
  }
  __syncthreads();

  // ---- build T[t][j] = k[t-j] (t>=j), overwrite EREG
  unsigned short* th = EREG;
  unsigned short* tl = EREG + MATSZ;
#pragma unroll
  for (int p = 0; p < 16; ++p) {
    int idx = tid + p*256;
    int t = idx >> 6, j = idx & 63;
    float v = (t >= j) ? kv[t - j] : 0.f;
    unsigned short hh = f2bf(v);
    th[t*PADJ + j] = hh; tl[t*PADJ + j] = f2bf(v - bf2f(hh));
  }
  __syncthreads();

  // ---- GEMM-C: y[col][t] += conv, then epilogue
  {
    const unsigned short* uh = UREG;
    const unsigned short* ul = UREG + MATSZ;
#pragma unroll
    for (int k0 = 0; k0 < 64; k0 += 32) {
      const int koff = k0 + 8*(l >> 4);
      const int trow = 16*w + (l & 15);
      bfrag8 bth = *(const bfrag8*)&th[trow*PADJ + koff];
      bfrag8 btl = *(const bfrag8*)&tl[trow*PADJ + koff];
#pragma unroll
      for (int mt = 0; mt < 4; ++mt) {
        const int arow = 16*mt + (l & 15);
        bfrag8 ah = *(const bfrag8*)&uh[arow*PADJ + koff];
        bfrag8 al = *(const bfrag8*)&ul[arow*PADJ + koff];
        acc[mt] = __builtin_amdgcn_mfma_f32_16x16x32_bf16(ah, bth, acc[mt], 0, 0, 0);
        acc[mt] = __builtin_amdgcn_mfma_f32_16x16x32_bf16(al, bth, acc[mt], 0, 0, 0);
        acc[mt] = __builtin_amdgcn_mfma_f32_16x16x32_bf16(ah, btl, acc[mt], 0, 0, 0);
      }
    }
    const int tg = 16*w + (l & 15);
#pragma unroll
    for (int mt = 0; mt < 4; ++mt)
#pragma unroll
      for (int r = 0; r < 4; ++r) {
        int colg = 16*mt + 4*(l >> 4) + r;
        float uval = bf2f(uh[colg*PADJ + tg]) + bf2f(ul[colg*PADJ + tg]);
        float pre = acc[mt][r] + uval*Dh;
        int b = 2*bp + (colg >> 5), c = colg & 31;
        zt[((size_t)(b*HDIM + h))*LSEQ + c*64 + tg] = gelu_tanh(pre);
      }
  }
}

// ---------------- GLU block
__global__ __launch_bounds__(256) void glu_kernel(
    const float* __restrict__ zt, const float* __restrict__ w,
    const float* __restrict__ bias, float* __restrict__ u) {
  __shared__ float As[32][132];
  __shared__ float Ba[32][68];
  __shared__ float Bg[32][68];
  const int r0 = blockIdx.x * 128;
  const int c0 = blockIdx.y * 64;
  const int b = r0 >> 11;
  const int l0 = r0 & (LSEQ-1);
  const int tid = threadIdx.x;
  const int tm = tid >> 4, tn = tid & 15;
  float acc_a[8][4] = {};
  float acc_g[8][4] = {};
  for (int k0 = 0; k0 < HDIM; k0 += 32) {
#pragma unroll
    for (int p = 0; p < 4; ++p) {
      int lin = tid + p*256;
      int m4 = lin & 31, k = lin >> 5;
      float4 v = *(const float4*)&zt[((size_t)(b*HDIM + k0 + k))*LSEQ + l0 + m4*4];
      *(float4*)&As[k][m4*4] = v;
    }
#pragma unroll
    for (int p = 0; p < 2; ++p) {
      int lin = tid + p*256;
      int n4 = lin & 15, k = lin >> 4;
      *(float4*)&Ba[k][n4*4] = *(const float4*)&w[(size_t)(k0+k)*512 + c0 + n4*4];
      *(float4*)&Bg[k][n4*4] = *(const float4*)&w[(size_t)(k0+k)*512 + 256 + c0 + n4*4];
    }
    __syncthreads();
#pragma unroll
    for (int k = 0; k < 32; ++k) {
      float4 a0 = *(const float4*)&As[k][tm*8];
      float4 a1 = *(const float4*)&As[k][tm*8+4];
      float4 bav = *(const float4*)&Ba[k][tn*4];
      float4 bgv = *(const float4*)&Bg[k][tn*4];
      float am[8] = {a0.x,a0.y,a0.z,a0.w,a1.x,a1.y,a1.z,a1.w};
      float bA[4] = {bav.x,bav.y,bav.z,bav.w};
      float bG[4] = {bgv.x,bgv.y,bgv.z,bgv.w};
#pragma unroll
      for (int i = 0; i < 8; ++i)
#pragma unroll
        for (int j = 0; j < 4; ++j) {
          acc_a[i][j] = fmaf(am[i], bA[j], acc_a[i][j]);
          acc_g[i][j] = fmaf(am[i], bG[j], acc_g[i][j]);
        }
    }
    __syncthreads();
  }
#pragma unroll
  for (int i = 0; i < 8; ++i) {
    int r = r0 + tm*8 + i;
    float4 res = *(const float4*)&u[(size_t)r*HDIM + c0 + tn*4];
    float rv[4] = {res.x,res.y,res.z,res.w};
    float o[4];
#pragma unroll
    for (int j = 0; j < 4; ++j) {
      int c = c0 + tn*4 + j;
      float wa = acc_a[i][j] + bias[c];
      float wg = acc_g[i][j] + bias[256 + c];
      float sig = 1.f/(1.f + expf(-wg));
      o[j] = rv[j] + wa*sig;
    }
    float4 ov = {o[0],o[1],o[2],o[3]};
    *(float4*)&u[(size_t)r*HDIM + c0 + tn*4] = ov;
  }
}

// ---------------- LayerNorm over H=256 per row -> un
__global__ __launch_bounds__(256) void ln_kernel(
    const float* __restrict__ u, const float* __restrict__ g,
    const float* __restrict__ b, float* __restrict__ un) {
  const int r0 = blockIdx.x * 8;
  const int w = threadIdx.x >> 6;
  const int lane = threadIdx.x & 63;
#pragma unroll
  for (int rr = 0; rr < 2; ++rr) {
    int r = r0 + w*2 + rr;
    float4 v = *(const float4*)&u[(size_t)r*HDIM + lane*4];
    float s = v.x+v.y+v.z+v.w;
    float sq = v.x*v.x + v.y*v.y + v.z*v.z + v.w*v.w;
    s = wave_sum64(s);
    sq = wave_sum64(sq);
    float mu = rdlane(s, 63) * (1.f/256.f);
    float ms = rdlane(sq, 63) * (1.f/256.f);
    float rstd = rsqrtf(ms - mu*mu + 1e-5f);
    float4 gg = *(const float4*)&g[lane*4];
    float4 bb = *(const float4*)&b[lane*4];
    float4 o;
    o.x = (v.x-mu)*rstd*gg.x + bb.x;
    o.y = (v.y-mu)*rstd*gg.y + bb.y;
    o.z = (v.z-mu)*rstd*gg.z + bb.z;
    o.w = (v.w-mu)*rstd*gg.w + bb.w;
    *(float4*)&un[(size_t)r*HDIM + lane*4] = o;
  }
}

// ---------------- head: un[16384,256] @ hw[256,204] + hb -> out
__global__ __launch_bounds__(256) void head_kernel(
    const float* __restrict__ un, const float* __restrict__ hw,
    const float* __restrict__ hb, float* __restrict__ out) {
  __shared__ float As[32][132];
  __shared__ float Bs[32][68];
  const int r0 = blockIdx.x * 128;
  const int c0 = blockIdx.y * 64;
  const int tid = threadIdx.x;
  const int tm = tid >> 4, tn = tid & 15;
  float acc[8][4] = {};
  for (int k0 = 0; k0 < HDIM; k0 += 32) {
#pragma unroll
    for (int p = 0; p < 16; ++p) {
      int lin = tid + p*256;
      int k = lin & 31, m = lin >> 5;
      As[k][m] = un[(size_t)(r0+m)*HDIM + k0 + k];
    }
#pragma unroll
    for (int p = 0; p < 8; ++p) {
      int lin = tid + p*256;
      int n = lin & 63, k = lin >> 6;
      int c = c0 + n;
      Bs[k][n] = (c < OUTC) ? hw[(size_t)(k0+k)*OUTC + c] : 0.f;
    }
    __syncthreads();
#pragma unroll
    for (int k = 0; k < 32; ++k) {
      float4 a0 = *(const float4*)&As[k][tm*8];
      float4 a1 = *(const float4*)&As[k][tm*8+4];
      float4 bv = *(const float4*)&Bs[k][tn*4];
      float am[8] = {a0.x,a0.y,a0.z,a0.w,a1.x,a1.y,a1.z,a1.w};
      float bb[4] = {bv.x,bv.y,bv.z,bv.w};
#pragma unroll
      for (int i = 0; i < 8; ++i)
#pragma unroll
        for (int j = 0; j < 4; ++j)
          acc[i][j] = fmaf(am[i], bb[j], acc[i][j]);
    }
    __syncthreads();
  }
#pragma unroll
  for (int i = 0; i < 8; ++i) {
    int r = r0 + tm*8 + i;
#pragma unroll
    for (int j = 0; j < 4; ++j) {
      int c = c0 + tn*4 + j;
      if (c < OUTC) out[(size_t)r*OUTC + c] = acc[i][j] + hb[c];
    }
  }
}

extern "C" void kernel_launch(void* const* d_in, const int* in_sizes, int n_in,
                              void* d_out, int out_size, void* d_ws, size_t ws_size,
                              hipStream_t stream) {
  const float* x       = (const float*)d_in[0];
  const float* proj_w  = (const float*)d_in[1];
  const float* proj_b  = (const float*)d_in[2];
  const float* log_dt  = (const float*)d_in[3];
  const float* lAr     = (const float*)d_in[4];
  const float* Aim     = (const float*)d_in[5];
  const float* Cre     = (const float*)d_in[6];
  const float* Cim     = (const float*)d_in[7];
  const float* Dp      = (const float*)d_in[8];
  const float* out_w   = (const float*)d_in[9];
  const float* out_b   = (const float*)d_in[10];
  const float* ln_g    = (const float*)d_in[11];
  const float* ln_b    = (const float*)d_in[12];
  const float* head_w  = (const float*)d_in[13];
  const float* head_b  = (const float*)d_in[14];
  float* outp = (float*)d_out;

  float* u    = (float*)d_ws;              // [16384,256]
  float* ut   = u  + (size_t)NROWS*HDIM;   // [B,H,L]
  float* zt   = ut + (size_t)NROWS*HDIM;   // [B,H,L]
  float* coef = zt + (size_t)NROWS*HDIM;   // [4][H*N]

  proj_kernel<<<NROWS/8, 256, 0, stream>>>(x, proj_w, proj_b, u);

  for (int d = 0; d < NDEPTH; ++d) {
    coef_kernel<<<HN/256, 256, 0, stream>>>(
        log_dt + d*HDIM, lAr + (size_t)d*HN, Aim + (size_t)d*HN,
        Cre + (size_t)d*HN, Cim + (size_t)d*HN, coef);
    dim3 tg(LSEQ/32, HDIM/32, NBATCH);
    transpose_LH_HL<<<tg, dim3(32,8), 0, stream>>>(u, ut);
    scan_mfma<<<dim3(HDIM, NBATCH/2), 256, 0, stream>>>(ut, coef, Dp + d*HDIM, zt);
    glu_kernel<<<dim3(NROWS/128, 4), 256, 0, stream>>>(
        zt, out_w + (size_t)d*HDIM*512, out_b + d*512, u);
  }

  ln_kernel<<<NROWS/8, 256, 0, stream>>>(u, ln_g, ln_b, ut);
  head_kernel<<<dim3(NROWS/128, 4), 256, 0, stream>>>(ut, head_w, head_b, outp);
}